// Round 16
// baseline (93.212 us; speedup 1.0000x reference)
//
#include <hip/hip_runtime.h>

#define BATCH 8
#define CH 256
#define HWSZ 1024
#define BHW 8192

typedef _Float16 f16;
typedef _Float16 f16x4 __attribute__((ext_vector_type(4)));
typedef _Float16 f16x8 __attribute__((ext_vector_type(8)));
typedef float f32x4 __attribute__((ext_vector_type(4)));
typedef unsigned long long u64;
typedef __attribute__((address_space(3))) unsigned int lds_u32;
typedef __attribute__((address_space(1))) const unsigned int glob_u32;

// ---------------- pgemmQKY: Q, K, Y from one x-tile; co-split; W prefetch; xpartial store ----------------
__global__ __launch_bounds__(256, 2) void pgemmQKY_kernel(
    const float* __restrict__ x,
    const float* __restrict__ Wq, const float* __restrict__ Wk, const float* __restrict__ Wo,
    const float* __restrict__ bq, const float* __restrict__ bk,
    f16* __restrict__ Qh, char* __restrict__ Ksw, f16* __restrict__ Yh,
    float* __restrict__ xpartial)
{
    __shared__ __align__(16) char kbuf[32 * 1024];
    __shared__ __align__(16) float xt[256][36];
    f16* tile = (f16*)&xt[0][0];
    char* tileb = (char*)&xt[0][0];

    const int bid  = blockIdx.x;
    const int h    = bid >> 8;
    const int p    = bid & 255;
    const int pxg0 = p * 32;
    const int b    = pxg0 >> 10;
    const int hw0  = pxg0 & 1023;
    const int tid  = threadIdx.x;
    const int lane = tid & 63;
    const int wid  = tid >> 6;
    const int m = lane & 15, g = lane >> 4;
    const int coW = h * 128;

    {
        const int f4 = tid & 7;
        const int cs = tid >> 3;
#pragma unroll
        for (int pass = 0; pass < 8; ++pass) {
            const int c = pass * 32 + cs;
            float4 v = *(const float4*)(x + ((size_t)b * CH + c) * HWSZ + hw0 + f4 * 4);
            *(float4*)&xt[c][f4 * 4] = v;
        }
    }
    __syncthreads();

    {
        const int px = tid & 31;
        const int q8 = tid >> 5;
        const int sw = (px & 7) << 4;
#pragma unroll
        for (int r = 0; r < 4; ++r) {
            f16x8 hi, lo;
#pragma unroll
            for (int i = 0; i < 8; ++i) {
                const int c = q8 * 32 + r * 8 + i;
                float v = xt[c][px];
                f16 hv = (f16)v;
                hi[i] = hv;
                lo[i] = (f16)(v - (float)hv);
            }
            const int base = q8 * 64 + r * 16;
            *(f16x8*)(kbuf + px * 1024 + (base ^ sw)) = hi;
            *(f16x8*)(kbuf + px * 1024 + 512 + (base ^ sw)) = lo;
        }
    }

    // per-tile column sums (exclusive slot per p — no memset/atomics needed)
    if (h == 0) {
        float s = 0.f;
#pragma unroll
        for (int i4 = 0; i4 < 8; ++i4) {
            float4 v = *(const float4*)&xt[tid][i4 * 4];
            s += v.x + v.y + v.z + v.w;
        }
        xpartial[p * 256 + tid] = s;
    }

    f16x8 aA[2][8], aB[2][8];
#define LOAD_W(dst, Wsel)                                                                \
    {                                                                                    \
        _Pragma("unroll")                                                                \
        for (int t = 0; t < 2; ++t)                                                      \
            _Pragma("unroll")                                                            \
            for (int kk = 0; kk < 8; ++kk) {                                             \
                const float* wrow = (Wsel) + (size_t)(coW + wid * 32 + t * 16 + m) * CH + kk * 32 + g * 8; \
                float4 w0 = *(const float4*)(wrow);                                      \
                float4 w1 = *(const float4*)(wrow + 4);                                  \
                f16x8 av;                                                                \
                av[0] = (f16)w0.x; av[1] = (f16)w0.y; av[2] = (f16)w0.z; av[3] = (f16)w0.w; \
                av[4] = (f16)w1.x; av[5] = (f16)w1.y; av[6] = (f16)w1.z; av[7] = (f16)w1.w; \
                dst[t][kk] = av;                                                         \
            }                                                                            \
    }
    LOAD_W(aA, Wq);
    __syncthreads();   // kbuf ready; all xt reads done

    const int sw0 = (m & 7) << 4;
    const f32x4 vz = {0.f, 0.f, 0.f, 0.f};
    f32x4 acc[2][2];

#define MFMA_PASS(ARR, NKS)                                                              \
    {                                                                                    \
        _Pragma("unroll")                                                                \
        for (int t = 0; t < 2; ++t) { acc[t][0] = vz; acc[t][1] = vz; }                  \
        _Pragma("unroll")                                                                \
        for (int ks = 0; ks < (NKS); ++ks) {                                             \
            const int X = ks * 64 + g * 16;                                              \
            f16x8 b0 = *(const f16x8*)(kbuf + m * 1024 + (X ^ sw0));                     \
            f16x8 b1 = *(const f16x8*)(kbuf + (16 + m) * 1024 + (X ^ sw0));              \
            _Pragma("unroll")                                                            \
            for (int t = 0; t < 2; ++t) {                                                \
                acc[t][0] = __builtin_amdgcn_mfma_f32_16x16x32_f16(ARR[t][ks & 7], b0, acc[t][0], 0, 0, 0); \
                acc[t][1] = __builtin_amdgcn_mfma_f32_16x16x32_f16(ARR[t][ks & 7], b1, acc[t][1], 0, 0, 0); \
            }                                                                            \
        }                                                                                \
    }

    // ---- Q pass (K=512 split) ----
    MFMA_PASS(aA, 16);
    LOAD_W(aB, Wk);   // prefetch K weights under Q epilogue

#pragma unroll
    for (int t = 0; t < 2; ++t) {
        const int lco0 = wid * 32 + t * 16 + 4 * g;
        float4 bv = *(const float4*)(bq + coW + lco0);
        float ba[4] = {bv.x, bv.y, bv.z, bv.w};
#pragma unroll
        for (int u = 0; u < 2; ++u) {
            const int px = u * 16 + m;
#pragma unroll
            for (int j = 0; j < 4; ++j)
                tile[(lco0 + j) * 32 + (px ^ (j << 3))] = (f16)(acc[t][u][j] + ba[j]);
        }
    }
    __syncthreads();
#pragma unroll
    for (int pass = 0; pass < 2; ++pass) {
        const int lco = pass * 64 + (tid >> 2);
        const int run = tid & 3;
        f16x8 v = *(const f16x8*)(tile + lco * 32 + ((run * 8) ^ ((lco & 3) << 3)));
        *(f16x8*)(Qh + ((size_t)b * CH + coW + lco) * HWSZ + hw0 + run * 8) = v;
    }

    // ---- K pass (K=512 split) ----
    MFMA_PASS(aB, 16);
    LOAD_W(aA, Wo);   // prefetch Y weights under K epilogue
    __syncthreads();

#pragma unroll
    for (int t = 0; t < 2; ++t) {
        const int lco0 = wid * 32 + t * 16 + 4 * g;
        float4 bv = *(const float4*)(bk + coW + lco0);
        float ba[4] = {bv.x, bv.y, bv.z, bv.w};
#pragma unroll
        for (int u = 0; u < 2; ++u) {
            const int px = u * 16 + m;
            f16x4 pk;
#pragma unroll
            for (int j = 0; j < 4; ++j) pk[j] = (f16)(acc[t][u][j] + ba[j]);
            *(f16x4*)(tileb + px * 256 + ((lco0 * 2) ^ (m << 3))) = pk;
        }
    }
    __syncthreads();
    {
        const int px = tid & 31;
        const int rp = tid >> 5;
        const int kloc = (px & 15) << 3;
        const int kglb = (px & 7) << 4;
        char* grow = Ksw + (size_t)(pxg0 + px) * 512 + h * 256;
#pragma unroll
        for (int i = 0; i < 2; ++i) {
            const int rl = rp + i * 8;
            u64 a0 = *(const u64*)(tileb + px * 256 + ((rl * 16) ^ kloc));
            u64 a1 = *(const u64*)(tileb + px * 256 + ((rl * 16 + 8) ^ kloc));
            char* gdst = grow + ((rl * 16) ^ kglb);
            *(u64*)gdst = a0;
            *(u64*)(gdst + 8) = a1;
        }
    }

    // ---- Y pass (hi-only, K=256; pre-gate, no bias) ----
    MFMA_PASS(aA, 8);
    __syncthreads();

#pragma unroll
    for (int t = 0; t < 2; ++t) {
        const int lco0 = wid * 32 + t * 16 + 4 * g;
#pragma unroll
        for (int u = 0; u < 2; ++u) {
            const int px = u * 16 + m;
#pragma unroll
            for (int j = 0; j < 4; ++j)
                tile[(lco0 + j) * 32 + (px ^ (j << 3))] = (f16)acc[t][u][j];
        }
    }
    __syncthreads();
#pragma unroll
    for (int pass = 0; pass < 2; ++pass) {
        const int lco = pass * 64 + (tid >> 2);
        const int run = tid & 3;
        f16x8 v = *(const f16x8*)(tile + lco * 32 + ((run * 8) ^ ((lco & 3) << 3)));
        *(f16x8*)(Yh + ((size_t)b * CH + coW + lco) * HWSZ + hw0 + run * 8) = v;
    }
#undef MFMA_PASS
#undef LOAD_W
}

// ---------------- score: r12/r15 MFMA body + fused ksum tail (batch==0 blocks) ----------------
// ksum[co] = Wk[co,:].(sum_p xpartial[p,:]/1024) + 8*bk[co]   (== sum_b kmean[b][co], exact)
__global__ __launch_bounds__(256, 2) void score_kernel(
    const f16* __restrict__ Qh, const char* __restrict__ Ksw,
    const float* __restrict__ Wk, const float* __restrict__ bk,
    const float* __restrict__ xpartial,
    float* __restrict__ rowdq, float* __restrict__ rowq)
{
    __shared__ __align__(16) char kbuf[2][32768];
    __shared__ float lds_rm[128][2];
    __shared__ float lds_dq[128];
    __shared__ float kmX[CH];
    __shared__ float kmS[CH];

    const int batch = blockIdx.x & 7;
    const int r0    = (blockIdx.x >> 3) * 128;
    const int tid   = threadIdx.x;
    const int lane  = tid & 63;
    const int wid   = tid >> 6;
    const int wr = wid >> 1, wc = wid & 1;
    const int m = lane & 15, g = lane >> 4;
    const int rbase = r0 + wr * 64;

    const char* kbase = Ksw + (size_t)batch * HWSZ * 512;

#define STAGE(buf, ch)                                                                   \
    {                                                                                    \
        const char* _src = kbase + (ch) * 64 * 512 + tid * 16;                           \
        char* _dst = &kbuf[buf][tid * 16];                                               \
        _Pragma("unroll")                                                                \
        for (int k = 0; k < 8; ++k)                                                      \
            __builtin_amdgcn_global_load_lds((glob_u32*)(_src + k * 4096),               \
                                             (lds_u32*)(_dst + k * 4096), 16, 0, 0);     \
    }

    STAGE(0, 0);

    f16x8 a[4][8];
#pragma unroll
    for (int t = 0; t < 4; ++t)
#pragma unroll
        for (int kk = 0; kk < 8; ++kk)
            a[t][kk] = *(const f16x8*)(Qh + (size_t)(rbase + t * 16 + m) * CH + kk * 32 + 8 * g);
#pragma unroll
    for (int t = 0; t < 4; ++t)
#pragma unroll
        for (int kk = 0; kk < 8; ++kk)
            asm volatile("" : "+v"(a[t][kk]));

    int Ebase[2];
    {
        const int low = ((g * 16) ^ ((m & 3) << 4)) + (((m >> 2) & 1) << 6);
#pragma unroll
        for (int u2 = 0; u2 < 2; ++u2)
            Ebase[u2] = (wc * 32 + u2 * 16 + m) * 512 + low;
    }

    float rm[4][4];
#pragma unroll
    for (int t = 0; t < 4; ++t)
#pragma unroll
        for (int jj = 0; jj < 4; ++jj) rm[t][jj] = -1e30f;

    int cur = 0;
    for (int ch = 0; ch < 16; ++ch) {
        if (ch < 15) {
            STAGE(cur ^ 1, ch + 1);
            asm volatile("s_waitcnt vmcnt(8)" ::: "memory");
        } else {
            asm volatile("s_waitcnt vmcnt(0)" ::: "memory");
        }
        __builtin_amdgcn_s_barrier();

        const char* kb = &kbuf[cur][0];
        f32x4 acc[4][2];
        const f32x4 vz = {0.f, 0.f, 0.f, 0.f};
#pragma unroll
        for (int t = 0; t < 4; ++t) { acc[t][0] = vz; acc[t][1] = vz; }

#pragma unroll
        for (int kk = 0; kk < 8; ++kk) {
            f16x8 bfr[2];
            const int xorb = (kk & 1) << 6;
            const int imm  = (kk >> 1) * 128;
            bfr[0] = *(const f16x8*)(kb + (Ebase[0] ^ xorb) + imm);
            bfr[1] = *(const f16x8*)(kb + (Ebase[1] ^ xorb) + imm);
#pragma unroll
            for (int t = 0; t < 4; ++t) {
                acc[t][0] = __builtin_amdgcn_mfma_f32_16x16x32_f16(a[t][kk], bfr[0], acc[t][0], 0, 0, 0);
                acc[t][1] = __builtin_amdgcn_mfma_f32_16x16x32_f16(a[t][kk], bfr[1], acc[t][1], 0, 0, 0);
            }
        }

#pragma unroll
        for (int t = 0; t < 4; ++t)
#pragma unroll
            for (int jj = 0; jj < 4; ++jj)
                rm[t][jj] = fmaxf(rm[t][jj], fmaxf(acc[t][0][jj], acc[t][1][jj]));

        asm volatile("" ::: "memory");
        __builtin_amdgcn_s_barrier();
        cur ^= 1;
    }
#undef STAGE

#pragma unroll
    for (int d = 1; d < 16; d <<= 1)
#pragma unroll
        for (int t = 0; t < 4; ++t)
#pragma unroll
            for (int jj = 0; jj < 4; ++jj)
                rm[t][jj] = fmaxf(rm[t][jj], __shfl_xor(rm[t][jj], d, 64));

    if (m == 0) {
#pragma unroll
        for (int t = 0; t < 4; ++t)
#pragma unroll
            for (int jj = 0; jj < 4; ++jj)
                lds_rm[wr * 64 + t * 16 + g * 4 + jj][wc] = rm[t][jj];
    }

    if (batch == 0) {
        // kmX[c] = (1/1024) * sum_p xpartial[p][c]  (coalesced: lanes read consecutive c)
        float xs[8] = {0.f, 0.f, 0.f, 0.f, 0.f, 0.f, 0.f, 0.f};
        for (int pp = 0; pp < 32; ++pp) {
#pragma unroll
            for (int j = 0; j < 8; ++j)
                xs[j] += xpartial[(pp * 8 + j) * 256 + tid];
        }
        float xstot = ((xs[0] + xs[1]) + (xs[2] + xs[3])) + ((xs[4] + xs[5]) + (xs[6] + xs[7]));
        kmX[tid] = xstot * (1.0f / 1024.0f);
        __syncthreads();

        // kmS[co] = Wk[co,:].kmX + 8*bk[co]
        float accw = 0.f;
        const float4* w = (const float4*)(Wk + (size_t)tid * CH);
        for (int c4 = 0; c4 < 64; ++c4) {
            float4 wv = w[c4];
            accw = fmaf(wv.x, kmX[c4 * 4 + 0], accw);
            accw = fmaf(wv.y, kmX[c4 * 4 + 1], accw);
            accw = fmaf(wv.z, kmX[c4 * 4 + 2], accw);
            accw = fmaf(wv.w, kmX[c4 * 4 + 3], accw);
        }
        kmS[tid] = accw + 8.0f * bk[tid];
        __syncthreads();

        float dq[4];
#pragma unroll
        for (int t = 0; t < 4; ++t) {
            float s = 0.f;
#pragma unroll
            for (int kk = 0; kk < 8; ++kk)
#pragma unroll
                for (int i = 0; i < 8; ++i)
                    s = fmaf((float)a[t][kk][i], kmS[kk * 32 + 8 * g + i], s);
            s += __shfl_xor(s, 16, 64);
            s += __shfl_xor(s, 32, 64);
            dq[t] = s;
        }
        if (wc == 0 && lane < 16) {
#pragma unroll
            for (int t = 0; t < 4; ++t)
                lds_dq[wr * 64 + t * 16 + lane] = dq[t];
        }
        __syncthreads();
        if (tid < 128) {
            rowq[r0 + tid] = lds_dq[tid];
            rowdq[(size_t)(r0 + tid) * 8] = fmaxf(lds_rm[tid][0], lds_rm[tid][1]);
        }
    } else {
        __syncthreads();
        if (tid < 128)
            rowdq[(size_t)(r0 + tid) * 8 + batch] = fmaxf(lds_rm[tid][0], lds_rm[tid][1]);
    }
}

// ---------------- gateYS: softmax (per-batch, block-local) + out = wgt*Y + bo ----------------
// 1024 blocks (2,097,152 / (256*8)); 128 blocks per batch, b block-uniform.
__global__ __launch_bounds__(256) void gateYS_kernel(const f16* __restrict__ Yh,
                                                     const float* __restrict__ rowdq,
                                                     const float* __restrict__ rowq,
                                                     const float* __restrict__ bo,
                                                     float* __restrict__ out)
{
    __shared__ float ld[HWSZ];
    __shared__ float red[256];

    const int tid = threadIdx.x;
    const size_t idx = ((size_t)blockIdx.x * 256 + tid) * 8;
    const int b  = (int)(idx >> 18);
    const int c  = (int)(idx >> 10) & 255;
    const int hw = (int)idx & 1023;

    // logits for batch b
    float l[4];
    float lmax = -1e30f;
#pragma unroll
    for (int i = 0; i < 4; ++i) {
        const size_t r = (size_t)b * HWSZ + i * 256 + tid;
        float4 v0 = *(const float4*)(rowdq + r * 8);
        float4 v1 = *(const float4*)(rowdq + r * 8 + 4);
        l[i] = (v0.x + v0.y + v0.z + v0.w + v1.x + v1.y + v1.z + v1.w + rowq[r]) * (1.0f / 128.0f);
        ld[i * 256 + tid] = l[i];
        lmax = fmaxf(lmax, l[i]);
    }
    red[tid] = lmax;
    __syncthreads();
    for (int s = 128; s > 0; s >>= 1) {
        if (tid < s) red[tid] = fmaxf(red[tid], red[tid + s]);
        __syncthreads();
    }
    const float mx = red[0];
    __syncthreads();

    float es = 0.f;
#pragma unroll
    for (int i = 0; i < 4; ++i) es += expf(l[i] - mx);
    red[tid] = es;
    __syncthreads();
    for (int s = 128; s > 0; s >>= 1) {
        if (tid < s) red[tid] += red[tid + s];
        __syncthreads();
    }
    const float inv = 1.0f / red[0];

    // gate this thread's 8 elements (same b, c; hw..hw+7)
    f16x8 y = *(const f16x8*)(Yh + idx);
    const float bov = bo[c];
    float4 o0, o1;
    o0.x = fmaf((float)y[0], expf(ld[hw + 0] - mx) * inv, bov);
    o0.y = fmaf((float)y[1], expf(ld[hw + 1] - mx) * inv, bov);
    o0.z = fmaf((float)y[2], expf(ld[hw + 2] - mx) * inv, bov);
    o0.w = fmaf((float)y[3], expf(ld[hw + 3] - mx) * inv, bov);
    o1.x = fmaf((float)y[4], expf(ld[hw + 4] - mx) * inv, bov);
    o1.y = fmaf((float)y[5], expf(ld[hw + 5] - mx) * inv, bov);
    o1.z = fmaf((float)y[6], expf(ld[hw + 6] - mx) * inv, bov);
    o1.w = fmaf((float)y[7], expf(ld[hw + 7] - mx) * inv, bov);
    *(float4*)(out + idx)     = o0;
    *(float4*)(out + idx + 4) = o1;
}

extern "C" void kernel_launch(void* const* d_in, const int* in_sizes, int n_in,
                              void* d_out, int out_size, void* d_ws, size_t ws_size,
                              hipStream_t stream)
{
    const float* x  = (const float*)d_in[0];
    const float* Wq = (const float*)d_in[1];
    const float* bq = (const float*)d_in[2];
    const float* Wk = (const float*)d_in[3];
    const float* bk = (const float*)d_in[4];
    const float* Wo = (const float*)d_in[5];
    const float* bo = (const float*)d_in[6];
    float* out = (float*)d_out;

    char* ws = (char*)d_ws;
    f16*   Qh       = (f16*)(ws);                                   // 4 MB
    char*  Ksw      = (char*)(ws + (4 << 20));                      // 4 MB (swizzled f16)
    f16*   Yh       = (f16*)(ws + (8 << 20));                       // 4 MB (pre-gate Y, f16)
    float* xpartial = (float*)(ws + (12 << 20));                    // 256 KB (exclusive writes)
    float* rowdq    = (float*)(ws + (12 << 20) + (256 << 10));      // 256 KB (exclusive writes)
    float* rowq     = (float*)(ws + (12 << 20) + (512 << 10));      // 32 KB

    pgemmQKY_kernel<<<dim3(512),  256, 0, stream>>>(x, Wq, Wk, Wo, bq, bk, Qh, Ksw, Yh, xpartial);
    score_kernel   <<<dim3(512),  256, 0, stream>>>(Qh, Ksw, Wk, bk, xpartial, rowdq, rowq);
    gateYS_kernel  <<<dim3(1024), 256, 0, stream>>>(Yh, rowdq, rowq, bo, out);
}

// Round 17
// 84.458 us; speedup vs baseline: 1.1036x; 1.1036x over previous
//
#include <hip/hip_runtime.h>

#define BATCH 8
#define CH 256
#define HWSZ 1024
#define BHW 8192

typedef _Float16 f16;
typedef _Float16 f16x4 __attribute__((ext_vector_type(4)));
typedef _Float16 f16x8 __attribute__((ext_vector_type(8)));
typedef float f32x4 __attribute__((ext_vector_type(4)));
typedef unsigned long long u64;
typedef __attribute__((address_space(3))) unsigned int lds_u32;
typedef __attribute__((address_space(1))) const unsigned int glob_u32;

// ---------------- pgemmQKY: Q, K, Y from one x-tile; co-split; W prefetch; xpartial store ----------------
__global__ __launch_bounds__(256, 2) void pgemmQKY_kernel(
    const float* __restrict__ x,
    const float* __restrict__ Wq, const float* __restrict__ Wk, const float* __restrict__ Wo,
    const float* __restrict__ bq, const float* __restrict__ bk,
    f16* __restrict__ Qh, char* __restrict__ Ksw, f16* __restrict__ Yh,
    float* __restrict__ xpartial)
{
    __shared__ __align__(16) char kbuf[32 * 1024];
    __shared__ __align__(16) float xt[256][36];
    f16* tile = (f16*)&xt[0][0];
    char* tileb = (char*)&xt[0][0];

    const int bid  = blockIdx.x;
    const int h    = bid >> 8;
    const int p    = bid & 255;
    const int pxg0 = p * 32;
    const int b    = pxg0 >> 10;
    const int hw0  = pxg0 & 1023;
    const int tid  = threadIdx.x;
    const int lane = tid & 63;
    const int wid  = tid >> 6;
    const int m = lane & 15, g = lane >> 4;
    const int coW = h * 128;

    {
        const int f4 = tid & 7;
        const int cs = tid >> 3;
#pragma unroll
        for (int pass = 0; pass < 8; ++pass) {
            const int c = pass * 32 + cs;
            float4 v = *(const float4*)(x + ((size_t)b * CH + c) * HWSZ + hw0 + f4 * 4);
            *(float4*)&xt[c][f4 * 4] = v;
        }
    }
    __syncthreads();

    {
        const int px = tid & 31;
        const int q8 = tid >> 5;
        const int sw = (px & 7) << 4;
#pragma unroll
        for (int r = 0; r < 4; ++r) {
            f16x8 hi, lo;
#pragma unroll
            for (int i = 0; i < 8; ++i) {
                const int c = q8 * 32 + r * 8 + i;
                float v = xt[c][px];
                f16 hv = (f16)v;
                hi[i] = hv;
                lo[i] = (f16)(v - (float)hv);
            }
            const int base = q8 * 64 + r * 16;
            *(f16x8*)(kbuf + px * 1024 + (base ^ sw)) = hi;
            *(f16x8*)(kbuf + px * 1024 + 512 + (base ^ sw)) = lo;
        }
    }

    // per-tile column sums (exclusive slot per p — no memset/atomics)
    if (h == 0) {
        float s = 0.f;
#pragma unroll
        for (int i4 = 0; i4 < 8; ++i4) {
            float4 v = *(const float4*)&xt[tid][i4 * 4];
            s += v.x + v.y + v.z + v.w;
        }
        xpartial[p * 256 + tid] = s;
    }

    f16x8 aA[2][8], aB[2][8];
#define LOAD_W(dst, Wsel)                                                                \
    {                                                                                    \
        _Pragma("unroll")                                                                \
        for (int t = 0; t < 2; ++t)                                                      \
            _Pragma("unroll")                                                            \
            for (int kk = 0; kk < 8; ++kk) {                                             \
                const float* wrow = (Wsel) + (size_t)(coW + wid * 32 + t * 16 + m) * CH + kk * 32 + g * 8; \
                float4 w0 = *(const float4*)(wrow);                                      \
                float4 w1 = *(const float4*)(wrow + 4);                                  \
                f16x8 av;                                                                \
                av[0] = (f16)w0.x; av[1] = (f16)w0.y; av[2] = (f16)w0.z; av[3] = (f16)w0.w; \
                av[4] = (f16)w1.x; av[5] = (f16)w1.y; av[6] = (f16)w1.z; av[7] = (f16)w1.w; \
                dst[t][kk] = av;                                                         \
            }                                                                            \
    }
    LOAD_W(aA, Wq);
    __syncthreads();   // kbuf ready; all xt reads done

    const int sw0 = (m & 7) << 4;
    const f32x4 vz = {0.f, 0.f, 0.f, 0.f};
    f32x4 acc[2][2];

#define MFMA_PASS(ARR, NKS)                                                              \
    {                                                                                    \
        _Pragma("unroll")                                                                \
        for (int t = 0; t < 2; ++t) { acc[t][0] = vz; acc[t][1] = vz; }                  \
        _Pragma("unroll")                                                                \
        for (int ks = 0; ks < (NKS); ++ks) {                                             \
            const int X = ks * 64 + g * 16;                                              \
            f16x8 b0 = *(const f16x8*)(kbuf + m * 1024 + (X ^ sw0));                     \
            f16x8 b1 = *(const f16x8*)(kbuf + (16 + m) * 1024 + (X ^ sw0));              \
            _Pragma("unroll")                                                            \
            for (int t = 0; t < 2; ++t) {                                                \
                acc[t][0] = __builtin_amdgcn_mfma_f32_16x16x32_f16(ARR[t][ks & 7], b0, acc[t][0], 0, 0, 0); \
                acc[t][1] = __builtin_amdgcn_mfma_f32_16x16x32_f16(ARR[t][ks & 7], b1, acc[t][1], 0, 0, 0); \
            }                                                                            \
        }                                                                                \
    }

    // ---- Q pass (K=512 split) ----
    MFMA_PASS(aA, 16);
    LOAD_W(aB, Wk);   // prefetch K weights under Q epilogue

#pragma unroll
    for (int t = 0; t < 2; ++t) {
        const int lco0 = wid * 32 + t * 16 + 4 * g;
        float4 bv = *(const float4*)(bq + coW + lco0);
        float ba[4] = {bv.x, bv.y, bv.z, bv.w};
#pragma unroll
        for (int u = 0; u < 2; ++u) {
            const int px = u * 16 + m;
#pragma unroll
            for (int j = 0; j < 4; ++j)
                tile[(lco0 + j) * 32 + (px ^ (j << 3))] = (f16)(acc[t][u][j] + ba[j]);
        }
    }
    __syncthreads();
#pragma unroll
    for (int pass = 0; pass < 2; ++pass) {
        const int lco = pass * 64 + (tid >> 2);
        const int run = tid & 3;
        f16x8 v = *(const f16x8*)(tile + lco * 32 + ((run * 8) ^ ((lco & 3) << 3)));
        *(f16x8*)(Qh + ((size_t)b * CH + coW + lco) * HWSZ + hw0 + run * 8) = v;
    }

    // ---- K pass (K=512 split) ----
    MFMA_PASS(aB, 16);
    LOAD_W(aA, Wo);   // prefetch Y weights under K epilogue
    __syncthreads();

#pragma unroll
    for (int t = 0; t < 2; ++t) {
        const int lco0 = wid * 32 + t * 16 + 4 * g;
        float4 bv = *(const float4*)(bk + coW + lco0);
        float ba[4] = {bv.x, bv.y, bv.z, bv.w};
#pragma unroll
        for (int u = 0; u < 2; ++u) {
            const int px = u * 16 + m;
            f16x4 pk;
#pragma unroll
            for (int j = 0; j < 4; ++j) pk[j] = (f16)(acc[t][u][j] + ba[j]);
            *(f16x4*)(tileb + px * 256 + ((lco0 * 2) ^ (m << 3))) = pk;
        }
    }
    __syncthreads();
    {
        const int px = tid & 31;
        const int rp = tid >> 5;
        const int kloc = (px & 15) << 3;
        const int kglb = (px & 7) << 4;
        char* grow = Ksw + (size_t)(pxg0 + px) * 512 + h * 256;
#pragma unroll
        for (int i = 0; i < 2; ++i) {
            const int rl = rp + i * 8;
            u64 a0 = *(const u64*)(tileb + px * 256 + ((rl * 16) ^ kloc));
            u64 a1 = *(const u64*)(tileb + px * 256 + ((rl * 16 + 8) ^ kloc));
            char* gdst = grow + ((rl * 16) ^ kglb);
            *(u64*)gdst = a0;
            *(u64*)(gdst + 8) = a1;
        }
    }

    // ---- Y pass (hi-only, K=256; pre-gate, no bias) ----
    MFMA_PASS(aA, 8);
    __syncthreads();

#pragma unroll
    for (int t = 0; t < 2; ++t) {
        const int lco0 = wid * 32 + t * 16 + 4 * g;
#pragma unroll
        for (int u = 0; u < 2; ++u) {
            const int px = u * 16 + m;
#pragma unroll
            for (int j = 0; j < 4; ++j)
                tile[(lco0 + j) * 32 + (px ^ (j << 3))] = (f16)acc[t][u][j];
        }
    }
    __syncthreads();
#pragma unroll
    for (int pass = 0; pass < 2; ++pass) {
        const int lco = pass * 64 + (tid >> 2);
        const int run = tid & 3;
        f16x8 v = *(const f16x8*)(tile + lco * 32 + ((run * 8) ^ ((lco & 3) << 3)));
        *(f16x8*)(Yh + ((size_t)b * CH + coW + lco) * HWSZ + hw0 + run * 8) = v;
    }
#undef MFMA_PASS
#undef LOAD_W
}

// ---------------- ksum: ksum[co] = Wk[co,:].(sum_p xpartial/1024) + 8*bk[co] ----------------
// grid 8 x 256: block covers 32 co; thread = (co-local = tid>>3, part = tid&7).
__global__ __launch_bounds__(256) void ksum_kernel(
    const float* __restrict__ Wk, const float* __restrict__ bk,
    const float* __restrict__ xpartial, float* __restrict__ ksum)
{
    __shared__ float kmX[CH];
    const int tid = threadIdx.x;

    // kmX[c] = (1/1024) * sum_p xpartial[p][c]  (coalesced over c)
    float s = 0.f;
    for (int p = 0; p < 256; ++p) s += xpartial[p * 256 + tid];
    kmX[tid] = s * (1.0f / 1024.0f);
    __syncthreads();

    const int co   = blockIdx.x * 32 + (tid >> 3);
    const int part = tid & 7;
    float acc = 0.f;
    const float4* w = (const float4*)(Wk + (size_t)co * CH + part * 32);
#pragma unroll
    for (int c4 = 0; c4 < 8; ++c4) {
        float4 wv = w[c4];
        const int c = part * 32 + c4 * 4;
        acc = fmaf(wv.x, kmX[c + 0], acc);
        acc = fmaf(wv.y, kmX[c + 1], acc);
        acc = fmaf(wv.z, kmX[c + 2], acc);
        acc = fmaf(wv.w, kmX[c + 3], acc);
    }
    acc += __shfl_xor(acc, 1, 64);
    acc += __shfl_xor(acc, 2, 64);
    acc += __shfl_xor(acc, 4, 64);
    if (part == 0) ksum[co] = acc + 8.0f * bk[co];
}

// ---------------- score: r15 exact (128 rows x 1024 cols, 256 thr, dbuf, counted vmcnt) ----------------
__global__ __launch_bounds__(256, 2) void score_kernel(
    const f16* __restrict__ Qh, const char* __restrict__ Ksw,
    const float* __restrict__ ksum, float* __restrict__ rowdq, float* __restrict__ rowq)
{
    __shared__ __align__(16) char kbuf[2][32768];
    __shared__ float lds_rm[128][2];
    __shared__ float lds_dq[128];
    __shared__ float kmS[CH];

    const int batch = blockIdx.x & 7;
    const int r0    = (blockIdx.x >> 3) * 128;
    const int tid   = threadIdx.x;
    const int lane  = tid & 63;
    const int wid   = tid >> 6;
    const int wr = wid >> 1, wc = wid & 1;
    const int m = lane & 15, g = lane >> 4;
    const int rbase = r0 + wr * 64;

    if (batch == 0) kmS[tid] = ksum[tid];

    const char* kbase = Ksw + (size_t)batch * HWSZ * 512;

#define STAGE(buf, ch)                                                                   \
    {                                                                                    \
        const char* _src = kbase + (ch) * 64 * 512 + tid * 16;                           \
        char* _dst = &kbuf[buf][tid * 16];                                               \
        _Pragma("unroll")                                                                \
        for (int k = 0; k < 8; ++k)                                                      \
            __builtin_amdgcn_global_load_lds((glob_u32*)(_src + k * 4096),               \
                                             (lds_u32*)(_dst + k * 4096), 16, 0, 0);     \
    }

    STAGE(0, 0);

    f16x8 a[4][8];
#pragma unroll
    for (int t = 0; t < 4; ++t)
#pragma unroll
        for (int kk = 0; kk < 8; ++kk)
            a[t][kk] = *(const f16x8*)(Qh + (size_t)(rbase + t * 16 + m) * CH + kk * 32 + 8 * g);
#pragma unroll
    for (int t = 0; t < 4; ++t)
#pragma unroll
        for (int kk = 0; kk < 8; ++kk)
            asm volatile("" : "+v"(a[t][kk]));

    int Ebase[2];
    {
        const int low = ((g * 16) ^ ((m & 3) << 4)) + (((m >> 2) & 1) << 6);
#pragma unroll
        for (int u2 = 0; u2 < 2; ++u2)
            Ebase[u2] = (wc * 32 + u2 * 16 + m) * 512 + low;
    }

    float rm[4][4];
#pragma unroll
    for (int t = 0; t < 4; ++t)
#pragma unroll
        for (int jj = 0; jj < 4; ++jj) rm[t][jj] = -1e30f;

    int cur = 0;
    for (int ch = 0; ch < 16; ++ch) {
        if (ch < 15) {
            STAGE(cur ^ 1, ch + 1);
            asm volatile("s_waitcnt vmcnt(8)" ::: "memory");
        } else {
            asm volatile("s_waitcnt vmcnt(0)" ::: "memory");
        }
        __builtin_amdgcn_s_barrier();

        const char* kb = &kbuf[cur][0];
        f32x4 acc[4][2];
        const f32x4 vz = {0.f, 0.f, 0.f, 0.f};
#pragma unroll
        for (int t = 0; t < 4; ++t) { acc[t][0] = vz; acc[t][1] = vz; }

#pragma unroll
        for (int kk = 0; kk < 8; ++kk) {
            f16x8 bfr[2];
            const int xorb = (kk & 1) << 6;
            const int imm  = (kk >> 1) * 128;
            bfr[0] = *(const f16x8*)(kb + (Ebase[0] ^ xorb) + imm);
            bfr[1] = *(const f16x8*)(kb + (Ebase[1] ^ xorb) + imm);
#pragma unroll
            for (int t = 0; t < 4; ++t) {
                acc[t][0] = __builtin_amdgcn_mfma_f32_16x16x32_f16(a[t][kk], bfr[0], acc[t][0], 0, 0, 0);
                acc[t][1] = __builtin_amdgcn_mfma_f32_16x16x32_f16(a[t][kk], bfr[1], acc[t][1], 0, 0, 0);
            }
        }

#pragma unroll
        for (int t = 0; t < 4; ++t)
#pragma unroll
            for (int jj = 0; jj < 4; ++jj)
                rm[t][jj] = fmaxf(rm[t][jj], fmaxf(acc[t][0][jj], acc[t][1][jj]));

        asm volatile("" ::: "memory");
        __builtin_amdgcn_s_barrier();
        cur ^= 1;
    }
#undef STAGE

#pragma unroll
    for (int d = 1; d < 16; d <<= 1)
#pragma unroll
        for (int t = 0; t < 4; ++t)
#pragma unroll
            for (int jj = 0; jj < 4; ++jj)
                rm[t][jj] = fmaxf(rm[t][jj], __shfl_xor(rm[t][jj], d, 64));

    if (m == 0) {
#pragma unroll
        for (int t = 0; t < 4; ++t)
#pragma unroll
            for (int jj = 0; jj < 4; ++jj)
                lds_rm[wr * 64 + t * 16 + g * 4 + jj][wc] = rm[t][jj];
    }

    if (batch == 0) {
        float dq[4];
#pragma unroll
        for (int t = 0; t < 4; ++t) {
            float s = 0.f;
#pragma unroll
            for (int kk = 0; kk < 8; ++kk)
#pragma unroll
                for (int i = 0; i < 8; ++i)
                    s = fmaf((float)a[t][kk][i], kmS[kk * 32 + 8 * g + i], s);
            s += __shfl_xor(s, 16, 64);
            s += __shfl_xor(s, 32, 64);
            dq[t] = s;
        }
        if (wc == 0 && lane < 16) {
#pragma unroll
            for (int t = 0; t < 4; ++t)
                lds_dq[wr * 64 + t * 16 + lane] = dq[t];
        }
        __syncthreads();
        if (tid < 128) {
            rowq[r0 + tid] = lds_dq[tid];
            rowdq[(size_t)(r0 + tid) * 8] = fmaxf(lds_rm[tid][0], lds_rm[tid][1]);
        }
    } else {
        __syncthreads();
        if (tid < 128)
            rowdq[(size_t)(r0 + tid) * 8 + batch] = fmaxf(lds_rm[tid][0], lds_rm[tid][1]);
    }
}

// ---------------- gateYS: softmax (per-batch, block-local) + out = wgt*Y + bo ----------------
__global__ __launch_bounds__(256) void gateYS_kernel(const f16* __restrict__ Yh,
                                                     const float* __restrict__ rowdq,
                                                     const float* __restrict__ rowq,
                                                     const float* __restrict__ bo,
                                                     float* __restrict__ out)
{
    __shared__ float ld[HWSZ];
    __shared__ float red[256];

    const int tid = threadIdx.x;
    const size_t idx = ((size_t)blockIdx.x * 256 + tid) * 8;
    const int b  = (int)(idx >> 18);
    const int c  = (int)(idx >> 10) & 255;
    const int hw = (int)idx & 1023;

    float l[4];
    float lmax = -1e30f;
#pragma unroll
    for (int i = 0; i < 4; ++i) {
        const size_t r = (size_t)b * HWSZ + i * 256 + tid;
        float4 v0 = *(const float4*)(rowdq + r * 8);
        float4 v1 = *(const float4*)(rowdq + r * 8 + 4);
        l[i] = (v0.x + v0.y + v0.z + v0.w + v1.x + v1.y + v1.z + v1.w + rowq[r]) * (1.0f / 128.0f);
        ld[i * 256 + tid] = l[i];
        lmax = fmaxf(lmax, l[i]);
    }
    red[tid] = lmax;
    __syncthreads();
    for (int s = 128; s > 0; s >>= 1) {
        if (tid < s) red[tid] = fmaxf(red[tid], red[tid + s]);
        __syncthreads();
    }
    const float mx = red[0];
    __syncthreads();

    float es = 0.f;
#pragma unroll
    for (int i = 0; i < 4; ++i) es += expf(l[i] - mx);
    red[tid] = es;
    __syncthreads();
    for (int s = 128; s > 0; s >>= 1) {
        if (tid < s) red[tid] += red[tid + s];
        __syncthreads();
    }
    const float inv = 1.0f / red[0];

    f16x8 y = *(const f16x8*)(Yh + idx);
    const float bov = bo[c];
    float4 o0, o1;
    o0.x = fmaf((float)y[0], expf(ld[hw + 0] - mx) * inv, bov);
    o0.y = fmaf((float)y[1], expf(ld[hw + 1] - mx) * inv, bov);
    o0.z = fmaf((float)y[2], expf(ld[hw + 2] - mx) * inv, bov);
    o0.w = fmaf((float)y[3], expf(ld[hw + 3] - mx) * inv, bov);
    o1.x = fmaf((float)y[4], expf(ld[hw + 4] - mx) * inv, bov);
    o1.y = fmaf((float)y[5], expf(ld[hw + 5] - mx) * inv, bov);
    o1.z = fmaf((float)y[6], expf(ld[hw + 6] - mx) * inv, bov);
    o1.w = fmaf((float)y[7], expf(ld[hw + 7] - mx) * inv, bov);
    *(float4*)(out + idx)     = o0;
    *(float4*)(out + idx + 4) = o1;
}

extern "C" void kernel_launch(void* const* d_in, const int* in_sizes, int n_in,
                              void* d_out, int out_size, void* d_ws, size_t ws_size,
                              hipStream_t stream)
{
    const float* x  = (const float*)d_in[0];
    const float* Wq = (const float*)d_in[1];
    const float* bq = (const float*)d_in[2];
    const float* Wk = (const float*)d_in[3];
    const float* bk = (const float*)d_in[4];
    const float* Wo = (const float*)d_in[5];
    const float* bo = (const float*)d_in[6];
    float* out = (float*)d_out;

    char* ws = (char*)d_ws;
    f16*   Qh       = (f16*)(ws);                                   // 4 MB
    char*  Ksw      = (char*)(ws + (4 << 20));                      // 4 MB (swizzled f16)
    f16*   Yh       = (f16*)(ws + (8 << 20));                       // 4 MB (pre-gate Y, f16)
    float* xpartial = (float*)(ws + (12 << 20));                    // 256 KB (exclusive writes)
    float* rowdq    = (float*)(ws + (12 << 20) + (256 << 10));      // 256 KB (exclusive writes)
    float* rowq     = (float*)(ws + (12 << 20) + (512 << 10));      // 32 KB
    float* ksum     = (float*)(ws + (12 << 20) + (544 << 10));      // 1 KB

    pgemmQKY_kernel<<<dim3(512),  256, 0, stream>>>(x, Wq, Wk, Wo, bq, bk, Qh, Ksw, Yh, xpartial);
    ksum_kernel    <<<dim3(8),    256, 0, stream>>>(Wk, bk, xpartial, ksum);
    score_kernel   <<<dim3(512),  256, 0, stream>>>(Qh, Ksw, ksum, rowdq, rowq);
    gateYS_kernel  <<<dim3(1024), 256, 0, stream>>>(Yh, rowdq, rowq, bo, out);
}